// Round 1
// baseline (1331.577 us; speedup 1.0000x reference)
//
#include <hip/hip_runtime.h>
#include <math.h>

#define BL 16384
#define D  512
#define K  4096

// ws layout (bytes)
#define OFF_C2     0            // 4096 f
#define OFF_X2     (16<<10)     // 16384 f
#define OFF_CNT    (80<<10)     // 4096 f
#define OFF_AVGC   (96<<10)     // 4096 f
#define OFF_SCAL   (112<<10)    // sumsq double @ +0, N float @ +8
#define OFF_KEYS   (128<<10)    // 16384 u64
#define OFF_DW     (256<<10)    // K*D f (becomes codebook_new in place)

// ---- row sum-of-squares (one wave per row) ----
__global__ void rowsq_kernel(const float* __restrict__ a, float* __restrict__ out)
{
    int row  = blockIdx.x;
    int lane = threadIdx.x;              // 64
    const float* p = a + (size_t)row * D;
    float s = 0.f;
#pragma unroll
    for (int j = 0; j < D / 64; ++j) {
        float v = p[lane + j * 64];
        s = fmaf(v, v, s);
    }
#pragma unroll
    for (int off = 32; off > 0; off >>= 1)
        s += __shfl_down(s, off, 64);
    if (lane == 0) out[row] = s;
}

// ---- fused GEMM + argmin: d2 = (x2 - 2*xc) + c2, mimicking reference rounding ----
// grid (256 row-tiles, 4 code-splits), 256 threads, 64x64x32 tiles, 4x4 microtile
__global__ __launch_bounds__(256) void argmin_kernel(
    const float* __restrict__ x, const float* __restrict__ cb,
    const float* __restrict__ x2, const float* __restrict__ c2,
    unsigned long long* __restrict__ keys)
{
    __shared__ __align__(16) float As[32][68];   // As[kk][row], pad 68 keeps 16B align
    __shared__ __align__(16) float Bs[32][68];   // Bs[kk][col]
    __shared__ float rv[64][16];
    __shared__ int   ri[64][16];

    const int tid  = threadIdx.x;
    const int tx   = tid & 15;          // code group
    const int ty   = tid >> 4;          // row group
    const int row0 = blockIdx.x * 64;
    const int nb   = blockIdx.y * 1024; // code split base

    float x2r[4];
#pragma unroll
    for (int m = 0; m < 4; ++m) x2r[m] = x2[row0 + ty * 4 + m];

    float minv[4];
    int   mini[4];
#pragma unroll
    for (int m = 0; m < 4; ++m) { minv[m] = 3.4028235e38f; mini[m] = 0; }

    for (int n0 = 0; n0 < 1024; n0 += 64) {
        float acc[4][4];
#pragma unroll
        for (int m = 0; m < 4; ++m)
#pragma unroll
            for (int n = 0; n < 4; ++n) acc[m][n] = 0.f;

        for (int d0 = 0; d0 < D; d0 += 32) {
            __syncthreads();   // previous iter's readers done before overwrite
#pragma unroll
            for (int j = 0; j < 2; ++j) {
                int v   = j * 256 + tid;       // float4 index 0..511
                int row = v >> 3;              // 0..63
                int col = (v & 7) * 4;         // 0,4,...,28
                float4 av = *(const float4*)(x  + (size_t)(row0 + row) * D + d0 + col);
                As[col + 0][row] = av.x; As[col + 1][row] = av.y;
                As[col + 2][row] = av.z; As[col + 3][row] = av.w;
                float4 bv = *(const float4*)(cb + (size_t)(nb + n0 + row) * D + d0 + col);
                Bs[col + 0][row] = bv.x; Bs[col + 1][row] = bv.y;
                Bs[col + 2][row] = bv.z; Bs[col + 3][row] = bv.w;
            }
            __syncthreads();
#pragma unroll
            for (int kk = 0; kk < 32; ++kk) {
                float4 a4 = *(const float4*)&As[kk][ty * 4];
                float4 b4 = *(const float4*)&Bs[kk][tx * 4];
                float a_[4] = { a4.x, a4.y, a4.z, a4.w };
                float b_[4] = { b4.x, b4.y, b4.z, b4.w };
#pragma unroll
                for (int m = 0; m < 4; ++m)
#pragma unroll
                    for (int n = 0; n < 4; ++n)
                        acc[m][n] = fmaf(a_[m], b_[n], acc[m][n]);
            }
        }
        // distance + running min (ascending k within thread -> first-occurrence ties)
#pragma unroll
        for (int n = 0; n < 4; ++n) {
            int kidx = nb + n0 + tx * 4 + n;
            float c2k = c2[kidx];
#pragma unroll
            for (int m = 0; m < 4; ++m) {
                float w  = x2r[m] - 2.0f * acc[m][n];  // rounds like reference (2*acc exact)
                float dd = w + c2k;                     // second rounding like reference
                if (dd < minv[m]) { minv[m] = dd; mini[m] = kidx; }
            }
        }
    }

    // cross-thread reduce (lowest index on ties), then cross-block via packed atomicMin
#pragma unroll
    for (int m = 0; m < 4; ++m) { rv[ty * 4 + m][tx] = minv[m]; ri[ty * 4 + m][tx] = mini[m]; }
    __syncthreads();
    if (tid < 64) {
        float bv = rv[tid][0]; int bi = ri[tid][0];
#pragma unroll
        for (int j = 1; j < 16; ++j) {
            float v = rv[tid][j]; int ii = ri[tid][j];
            if (v < bv || (v == bv && ii < bi)) { bv = v; bi = ii; }
        }
        // d2 > 0 so float bits are order-preserving; 12 low bits hold k (lower k wins ties)
        unsigned long long key =
            ((unsigned long long)__float_as_uint(bv) << 12) | (unsigned long long)bi;
        atomicMin(&keys[row0 + tid], key);
    }
}

// ---- scatter: counts[k] += 1, dw[k,:] += x[row,:] ----
__global__ __launch_bounds__(256) void scatter_kernel(
    const float* __restrict__ x, const unsigned long long* __restrict__ keys,
    float* __restrict__ dw, float* __restrict__ counts)
{
    int row = blockIdx.x;
    int tid = threadIdx.x;
    int k   = (int)(keys[row] & 0xFFFULL);
    if (tid == 0) atomicAdd(&counts[k], 1.0f);
    const float* xp = x + (size_t)row * D;
    float* dp = dw + (size_t)k * D;
    atomicAdd(dp + tid,        xp[tid]);
    atomicAdd(dp + tid + 256,  xp[tid + 256]);
}

// ---- EMA cluster + N = sum(avg_cluster) ----
__global__ __launch_bounds__(256) void ema_cluster_kernel(
    const float* __restrict__ hc, const float* __restrict__ counts,
    const float* __restrict__ countp, float* __restrict__ avgc, float* __restrict__ Nout)
{
    __shared__ float sm[256];
    int i = blockIdx.x * 256 + threadIdx.x;
    const float om = 1.0f - 0.99f;                  // match reference's (one - decay)
    float bias = 1.0f - powf(0.99f, countp[0] + 1.0f);
    float a = (hc[i] * 0.99f + om * counts[i]) / bias;
    avgc[i] = a;
    sm[threadIdx.x] = a;
    __syncthreads();
    for (int s = 128; s > 0; s >>= 1) {
        if (threadIdx.x < s) sm[threadIdx.x] += sm[threadIdx.x + s];
        __syncthreads();
    }
    if (threadIdx.x == 0) atomicAdd(Nout, sm[0]);
}

// ---- EMA dw + codebook_new (in place over dw) ----
__global__ __launch_bounds__(256) void ema_dw_kernel(
    const float* __restrict__ hdw, float* __restrict__ dw,
    const float* __restrict__ avgc, const float* __restrict__ Nptr,
    const float* __restrict__ countp)
{
    size_t i = (size_t)blockIdx.x * 256 + threadIdx.x;
    const float om = 1.0f - 0.99f;
    float bias = 1.0f - powf(0.99f, countp[0] + 1.0f);
    float N = *Nptr;
    int k = (int)(i >> 9);
    float avg_dw = (hdw[i] * 0.99f + om * dw[i]) / bias;
    float cc = ((avgc[k] + 1e-5f) / (N + 0.04096f)) * N;
    dw[i] = avg_dw / cc;
}

// ---- gather codebook_new rows -> quantized, accumulate loss ----
__global__ __launch_bounds__(256) void gather_kernel(
    const float* __restrict__ x, const unsigned long long* __restrict__ keys,
    const float* __restrict__ cbn, float* __restrict__ outq, double* __restrict__ sumsq)
{
    __shared__ float sm[256];
    int row = blockIdx.x;
    int tid = threadIdx.x;
    int k   = (int)(keys[row] & 0xFFFULL);
    const float* xp = x   + (size_t)row * D;
    const float* cp = cbn + (size_t)k   * D;
    float* op = outq + (size_t)row * D;
    float local = 0.f;
#pragma unroll
    for (int j = 0; j < 2; ++j) {
        int d = tid + j * 256;
        float xv = xp[d];
        float q  = cp[d];
        float quant = xv + (q - xv);   // reference's x + (q - x)
        op[d] = quant;
        float diff = xv - quant;
        local = fmaf(diff, diff, local);
    }
    sm[tid] = local;
    __syncthreads();
    for (int s = 128; s > 0; s >>= 1) {
        if (tid < s) sm[tid] += sm[tid + s];
        __syncthreads();
    }
    if (tid == 0) atomicAdd(sumsq, (double)sm[0]);
}

// ---- finalize: loss scalar + indices as float ----
__global__ void finalize_kernel(const unsigned long long* __restrict__ keys,
                                const double* __restrict__ sumsq, float* __restrict__ out)
{
    int i = blockIdx.x * 256 + threadIdx.x;   // grid 64 -> 16384
    out[8388609 + i] = (float)(keys[i] & 0xFFFULL);
    if (i == 0) out[8388608] = (float)(0.5 * (*sumsq) / 8388608.0);
}

extern "C" void kernel_launch(void* const* d_in, const int* in_sizes, int n_in,
                              void* d_out, int out_size, void* d_ws, size_t ws_size,
                              hipStream_t stream)
{
    const float* x   = (const float*)d_in[0];
    const float* cb  = (const float*)d_in[1];
    const float* hc  = (const float*)d_in[2];
    const float* hdw = (const float*)d_in[3];
    const float* cnt = (const float*)d_in[4];
    float* out = (float*)d_out;

    char* ws = (char*)d_ws;
    float*  c2     = (float*)(ws + OFF_C2);
    float*  x2     = (float*)(ws + OFF_X2);
    float*  counts = (float*)(ws + OFF_CNT);
    float*  avgc   = (float*)(ws + OFF_AVGC);
    double* sumsq  = (double*)(ws + OFF_SCAL);
    float*  Nout   = (float*)(ws + OFF_SCAL + 8);
    unsigned long long* keys = (unsigned long long*)(ws + OFF_KEYS);
    float*  dw     = (float*)(ws + OFF_DW);

    hipMemsetAsync(ws + OFF_CNT,  0,    (48 << 10),       stream);  // counts/avgc/scalars
    hipMemsetAsync(ws + OFF_KEYS, 0xFF, BL * 8,           stream);  // keys = UINT64_MAX
    hipMemsetAsync(ws + OFF_DW,   0,    (size_t)K * D * 4, stream); // dw accumulator

    rowsq_kernel<<<K,  64, 0, stream>>>(cb, c2);
    rowsq_kernel<<<BL, 64, 0, stream>>>(x, x2);
    argmin_kernel<<<dim3(BL / 64, 4), 256, 0, stream>>>(x, cb, x2, c2, keys);
    scatter_kernel<<<BL, 256, 0, stream>>>(x, keys, dw, counts);
    ema_cluster_kernel<<<K / 256, 256, 0, stream>>>(hc, counts, cnt, avgc, Nout);
    ema_dw_kernel<<<(K * D) / 256, 256, 0, stream>>>(hdw, dw, avgc, Nout, cnt);
    gather_kernel<<<BL, 256, 0, stream>>>(x, keys, dw, out, sumsq);
    finalize_kernel<<<BL / 256, 256, 0, stream>>>(keys, sumsq, out);
}

// Round 2
// 731.383 us; speedup vs baseline: 1.8206x; 1.8206x over previous
//
#include <hip/hip_runtime.h>
#include <math.h>

#define BL 16384
#define D  512
#define K  4096

// ---- primary ws layout (bytes) ----
#define OFF_C2    0                         // 4096 f
#define OFF_X2    (16<<10)                  // 16384 f
#define OFF_CNT   (80<<10)                  // 4096 f
#define OFF_AVGC  (96<<10)                  // 4096 f
#define OFF_SCAL  (112<<10)                 // sumsq double @+0, N float @+8
#define OFF_KEYS  (128<<10)                 // 16384 u64
#define OFF_CAND  (256<<10)                 // 16384*8 u16
#define OFF_CH    (512<<10)                 // K*D bf16
#define OFF_CL    ((512<<10) + K*D*2)       // K*D bf16
#define OFF_CBN   OFF_CH                    // K*D f32 (reuses ch/cl after argmin)
// ---- fallback: round-1-proven footprint (<= 8,650,752 B) ----
#define OFF_CBN_FB (256<<10)

typedef __bf16 bf16x8 __attribute__((ext_vector_type(8)));
typedef float  f32x4  __attribute__((ext_vector_type(4)));
#define MFMA(a,b,c) __builtin_amdgcn_mfma_f32_16x16x32_bf16(a,b,c,0,0,0)

// ================= shared-with-round-1 kernels (bit-exact, do not touch) ====

// row sum-of-squares — MUST stay bit-identical to round 1 (x2/c2 feed rescore)
__global__ void rowsq_kernel(const float* __restrict__ a, float* __restrict__ out)
{
    int row  = blockIdx.x;
    int lane = threadIdx.x;              // 64
    const float* p = a + (size_t)row * D;
    float s = 0.f;
#pragma unroll
    for (int j = 0; j < D / 64; ++j) {
        float v = p[lane + j * 64];
        s = fmaf(v, v, s);
    }
#pragma unroll
    for (int off = 32; off > 0; off >>= 1)
        s += __shfl_down(s, off, 64);
    if (lane == 0) out[row] = s;
}

// ================= primary path ============================================

__device__ __forceinline__ unsigned short f2bf_rne(float f) {
    unsigned u = __float_as_uint(f);
    unsigned r = u + 0x7FFFu + ((u >> 16) & 1u);
    return (unsigned short)(r >> 16);
}

// fp32 -> (bf16 hi, bf16 lo) split, flat, 8 elems/thread
__global__ __launch_bounds__(256) void split_kernel(
    const float* __restrict__ src, unsigned short* __restrict__ h,
    unsigned short* __restrict__ lo)
{
    size_t base = ((size_t)blockIdx.x * 256 + threadIdx.x) * 8;
    float4 v0 = *(const float4*)(src + base);
    float4 v1 = *(const float4*)(src + base + 4);
    float f[8] = {v0.x,v0.y,v0.z,v0.w,v1.x,v1.y,v1.z,v1.w};
    __align__(16) unsigned short hh[8], ll[8];
#pragma unroll
    for (int j = 0; j < 8; ++j) {
        unsigned short hb = f2bf_rne(f[j]);
        hh[j] = hb;
        float hf = __uint_as_float((unsigned)hb << 16);
        ll[j] = f2bf_rne(f[j] - hf);   // exact residual, then RNE to bf16
    }
    *(uint4*)(h  + base) = *(const uint4*)hh;
    *(uint4*)(lo + base) = *(const uint4*)ll;
}

#define LDA 72   // ushort row stride: 64 data + 8 pad (72%8==0 -> 16B aligned, banks spread)

// MFMA approx distance + per-split top-2 capture.
// block: 64 rows x 1024 codes (blockIdx.y = split), 256 thr = 4 waves (2x2 over 64x64 chunk)
__global__ __launch_bounds__(256, 4) void argmin_mfma(
    const unsigned short* __restrict__ xh, const unsigned short* __restrict__ xl,
    const unsigned short* __restrict__ ch, const unsigned short* __restrict__ cl,
    const float* __restrict__ x2, const float* __restrict__ c2,
    unsigned short* __restrict__ cand)
{
    __shared__ __align__(16) unsigned short sAh[64*LDA];
    __shared__ __align__(16) unsigned short sAl[64*LDA];
    __shared__ __align__(16) unsigned short sBh[64*LDA];
    __shared__ __align__(16) unsigned short sBl[64*LDA];

    const int tid = threadIdx.x;
    const int l   = tid & 63;
    const int w   = tid >> 6;
    const int q   = l >> 4;          // quad
    const int c   = l & 15;          // col-lane
    const int wm  = w >> 1, wn = w & 1;
    const int row0 = blockIdx.x * 64;
    const int nb   = blockIdx.y * 1024;

    // staging: 512 groups of 8 bf16 per array; thread does groups tid and tid+256
    const int sr0 = tid >> 3,          sk0 = (tid & 7) * 8;
    const int sr1 = (tid + 256) >> 3,  sk1 = (tid & 7) * 8;

    // fragment LDS offsets (ushort units); +32 selects k-half
    int offA0 = (wm*32 +  0 + c) * LDA + q*8;
    int offA1 = (wm*32 + 16 + c) * LDA + q*8;
    int offB0 = (wn*32 +  0 + c) * LDA + q*8;
    int offB1 = (wn*32 + 16 + c) * LDA + q*8;

    float x2r[8];
#pragma unroll
    for (int tm = 0; tm < 2; ++tm)
#pragma unroll
        for (int r = 0; r < 4; ++r)
            x2r[tm*4+r] = x2[row0 + wm*32 + tm*16 + q*4 + r];

    float v1[8], v2[8]; unsigned i1[8], i2[8];
#pragma unroll
    for (int s = 0; s < 8; ++s) { v1[s] = v2[s] = 3.4028235e38f; i1[s] = i2[s] = 0; }

    for (int n0 = 0; n0 < 1024; n0 += 64) {
        f32x4 acc[2][2];
#pragma unroll
        for (int tm = 0; tm < 2; ++tm)
#pragma unroll
            for (int tn = 0; tn < 2; ++tn) { f32x4 z = {0.f,0.f,0.f,0.f}; acc[tm][tn] = z; }

        for (int d0 = 0; d0 < D; d0 += 64) {
            __syncthreads();   // prior readers done
            {
                size_t ga0 = (size_t)(row0 + sr0) * D + d0 + sk0;
                size_t ga1 = (size_t)(row0 + sr1) * D + d0 + sk1;
                size_t gb0 = (size_t)(nb + n0 + sr0) * D + d0 + sk0;
                size_t gb1 = (size_t)(nb + n0 + sr1) * D + d0 + sk1;
                *(uint4*)&sAh[sr0*LDA + sk0] = *(const uint4*)&xh[ga0];
                *(uint4*)&sAl[sr0*LDA + sk0] = *(const uint4*)&xl[ga0];
                *(uint4*)&sBh[sr0*LDA + sk0] = *(const uint4*)&ch[gb0];
                *(uint4*)&sBl[sr0*LDA + sk0] = *(const uint4*)&cl[gb0];
                *(uint4*)&sAh[sr1*LDA + sk1] = *(const uint4*)&xh[ga1];
                *(uint4*)&sAl[sr1*LDA + sk1] = *(const uint4*)&xl[ga1];
                *(uint4*)&sBh[sr1*LDA + sk1] = *(const uint4*)&ch[gb1];
                *(uint4*)&sBl[sr1*LDA + sk1] = *(const uint4*)&cl[gb1];
            }
            __syncthreads();
#pragma unroll
            for (int kh = 0; kh < 2; ++kh) {
                const int ko = kh * 32;
                bf16x8 ah0 = *(const bf16x8*)&sAh[offA0 + ko];
                bf16x8 ah1 = *(const bf16x8*)&sAh[offA1 + ko];
                bf16x8 al0 = *(const bf16x8*)&sAl[offA0 + ko];
                bf16x8 al1 = *(const bf16x8*)&sAl[offA1 + ko];
                bf16x8 bh0 = *(const bf16x8*)&sBh[offB0 + ko];
                bf16x8 bh1 = *(const bf16x8*)&sBh[offB1 + ko];
                bf16x8 bl0 = *(const bf16x8*)&sBl[offB0 + ko];
                bf16x8 bl1 = *(const bf16x8*)&sBl[offB1 + ko];
                acc[0][0] = MFMA(ah0, bh0, acc[0][0]);
                acc[0][0] = MFMA(ah0, bl0, acc[0][0]);
                acc[0][0] = MFMA(al0, bh0, acc[0][0]);
                acc[0][1] = MFMA(ah0, bh1, acc[0][1]);
                acc[0][1] = MFMA(ah0, bl1, acc[0][1]);
                acc[0][1] = MFMA(al0, bh1, acc[0][1]);
                acc[1][0] = MFMA(ah1, bh0, acc[1][0]);
                acc[1][0] = MFMA(ah1, bl0, acc[1][0]);
                acc[1][0] = MFMA(al1, bh0, acc[1][0]);
                acc[1][1] = MFMA(ah1, bh1, acc[1][1]);
                acc[1][1] = MFMA(ah1, bl1, acc[1][1]);
                acc[1][1] = MFMA(al1, bh1, acc[1][1]);
            }
        }
        // chunk epilogue: approx dd + running top-2 (C layout: col=lane&15, row=quad*4+reg)
#pragma unroll
        for (int tm = 0; tm < 2; ++tm)
#pragma unroll
            for (int tn = 0; tn < 2; ++tn) {
                unsigned col = nb + n0 + wn*32 + tn*16 + c;
                float c2v = c2[col];
#pragma unroll
                for (int r = 0; r < 4; ++r) {
                    int s = tm*4 + r;
                    float dd = (x2r[s] - 2.0f * acc[tm][tn][r]) + c2v;
                    bool lt1 = (dd < v1[s]) || (dd == v1[s] && col < i1[s]);
                    bool lt2 = (dd < v2[s]) || (dd == v2[s] && col < i2[s]);
                    if (lt1)      { v2[s]=v1[s]; i2[s]=i1[s]; v1[s]=dd; i1[s]=col; }
                    else if (lt2) { v2[s]=dd;    i2[s]=col; }
                }
            }
    }

    // butterfly top-2 merge across the 16 col-lanes (same quad keeps same rows)
#pragma unroll
    for (int s = 0; s < 8; ++s) {
#pragma unroll
        for (int m = 1; m < 16; m <<= 1) {
            float    ov1 = __shfl_xor(v1[s], m, 64);
            unsigned oi1 = __shfl_xor(i1[s], m, 64);
            float    ov2 = __shfl_xor(v2[s], m, 64);
            unsigned oi2 = __shfl_xor(i2[s], m, 64);
            bool oLt = (ov1 < v1[s]) || (ov1 == v1[s] && oi1 < i1[s]);
            float    a1  = oLt ? ov1 : v1[s];  unsigned ai1 = oLt ? oi1 : i1[s];
            float    lf  = oLt ? v1[s] : ov1;  unsigned lfi = oLt ? i1[s] : oi1;  // loser of firsts
            float    ws_ = oLt ? ov2 : v2[s];  unsigned wsi = oLt ? oi2 : i2[s];  // winner's second
            bool s2 = (ws_ < lf) || (ws_ == lf && wsi < lfi);
            v2[s] = s2 ? ws_ : lf;  i2[s] = s2 ? wsi : lfi;
            v1[s] = a1;             i1[s] = ai1;
        }
    }

    // cross-wave merge via LDS (reuse sAh after a barrier), then write candidates
    __syncthreads();
    float*    mbv = (float*)sAh;            // [64][2][2]
    unsigned* mbi = (unsigned*)&sAh[2048];  // [64][2][2]
    if (c == 0) {
#pragma unroll
        for (int s = 0; s < 8; ++s) {
            int tm = s >> 2, r = s & 3;
            int rl = wm*32 + tm*16 + q*4 + r;
            mbv[(rl*2 + wn)*2 + 0] = v1[s];  mbv[(rl*2 + wn)*2 + 1] = v2[s];
            mbi[(rl*2 + wn)*2 + 0] = i1[s];  mbi[(rl*2 + wn)*2 + 1] = i2[s];
        }
    }
    __syncthreads();
    if (tid < 64) {
        float    p1 = mbv[(tid*2+0)*2+0], p2 = mbv[(tid*2+0)*2+1];
        unsigned pi1 = mbi[(tid*2+0)*2+0], pi2 = mbi[(tid*2+0)*2+1];
        float    q1 = mbv[(tid*2+1)*2+0], q2 = mbv[(tid*2+1)*2+1];
        unsigned qi1 = mbi[(tid*2+1)*2+0], qi2 = mbi[(tid*2+1)*2+1];
        bool qLt = (q1 < p1) || (q1 == p1 && qi1 < pi1);
        float    b1  = qLt ? q1 : p1;   unsigned b1i = qLt ? qi1 : pi1;
        float    lf  = qLt ? p1 : q1;   unsigned lfi = qLt ? pi1 : qi1;
        float    ws_ = qLt ? q2 : p2;   unsigned wsi = qLt ? qi2 : pi2;
        bool s2 = (ws_ < lf) || (ws_ == lf && wsi < lfi);
        unsigned b2i = s2 ? wsi : lfi;
        size_t base = (size_t)(row0 + tid) * 8 + blockIdx.y * 2;
        cand[base + 0] = (unsigned short)b1i;
        cand[base + 1] = (unsigned short)b2i;
    }
}

// exact rescore: bit-identical to round-1 arithmetic (sequential fmaf k=0..511),
// packed-key atomicMin reproduces round-1 tie semantics exactly.
__global__ __launch_bounds__(256) void rescore_kernel(
    const float* __restrict__ x, const float* __restrict__ cb,
    const float* __restrict__ x2, const float* __restrict__ c2,
    const unsigned short* __restrict__ cand,
    unsigned long long* __restrict__ keys)
{
    int t = blockIdx.x * 256 + threadIdx.x;  // 131072
    int row = t >> 3, ci = t & 7;
    int idx = cand[(size_t)row * 8 + ci];
    const float* xp = x  + (size_t)row * D;
    const float* cp = cb + (size_t)idx * D;
    float acc = 0.f;
#pragma unroll 4
    for (int k0 = 0; k0 < D; k0 += 4) {
        float4 xv = *(const float4*)(xp + k0);
        float4 cv = *(const float4*)(cp + k0);
        acc = fmaf(xv.x, cv.x, acc);
        acc = fmaf(xv.y, cv.y, acc);
        acc = fmaf(xv.z, cv.z, acc);
        acc = fmaf(xv.w, cv.w, acc);
    }
    float wv = x2[row] - 2.0f * acc;
    float dd = wv + c2[idx];
    unsigned long long key =
        ((unsigned long long)__float_as_uint(dd) << 12) | (unsigned long long)idx;
    atomicMin(&keys[row], key);
}

// ================= fallback argmin (round-1 verbatim, proven) ===============
__global__ __launch_bounds__(256) void argmin_fb(
    const float* __restrict__ x, const float* __restrict__ cb,
    const float* __restrict__ x2, const float* __restrict__ c2,
    unsigned long long* __restrict__ keys)
{
    __shared__ __align__(16) float As[32][68];
    __shared__ __align__(16) float Bs[32][68];
    __shared__ float rv[64][16];
    __shared__ int   ri[64][16];

    const int tid  = threadIdx.x;
    const int tx   = tid & 15;
    const int ty   = tid >> 4;
    const int row0 = blockIdx.x * 64;
    const int nb   = blockIdx.y * 1024;

    float x2r[4];
#pragma unroll
    for (int m = 0; m < 4; ++m) x2r[m] = x2[row0 + ty * 4 + m];

    float minv[4]; int mini[4];
#pragma unroll
    for (int m = 0; m < 4; ++m) { minv[m] = 3.4028235e38f; mini[m] = 0; }

    for (int n0 = 0; n0 < 1024; n0 += 64) {
        float acc[4][4];
#pragma unroll
        for (int m = 0; m < 4; ++m)
#pragma unroll
            for (int n = 0; n < 4; ++n) acc[m][n] = 0.f;

        for (int d0 = 0; d0 < D; d0 += 32) {
            __syncthreads();
#pragma unroll
            for (int j = 0; j < 2; ++j) {
                int v   = j * 256 + tid;
                int row = v >> 3;
                int col = (v & 7) * 4;
                float4 av = *(const float4*)(x  + (size_t)(row0 + row) * D + d0 + col);
                As[col + 0][row] = av.x; As[col + 1][row] = av.y;
                As[col + 2][row] = av.z; As[col + 3][row] = av.w;
                float4 bv = *(const float4*)(cb + (size_t)(nb + n0 + row) * D + d0 + col);
                Bs[col + 0][row] = bv.x; Bs[col + 1][row] = bv.y;
                Bs[col + 2][row] = bv.z; Bs[col + 3][row] = bv.w;
            }
            __syncthreads();
#pragma unroll
            for (int kk = 0; kk < 32; ++kk) {
                float4 a4 = *(const float4*)&As[kk][ty * 4];
                float4 b4 = *(const float4*)&Bs[kk][tx * 4];
                float a_[4] = { a4.x, a4.y, a4.z, a4.w };
                float b_[4] = { b4.x, b4.y, b4.z, b4.w };
#pragma unroll
                for (int m = 0; m < 4; ++m)
#pragma unroll
                    for (int n = 0; n < 4; ++n)
                        acc[m][n] = fmaf(a_[m], b_[n], acc[m][n]);
            }
        }
#pragma unroll
        for (int n = 0; n < 4; ++n) {
            int kidx = nb + n0 + tx * 4 + n;
            float c2k = c2[kidx];
#pragma unroll
            for (int m = 0; m < 4; ++m) {
                float w  = x2r[m] - 2.0f * acc[m][n];
                float dd = w + c2k;
                if (dd < minv[m]) { minv[m] = dd; mini[m] = kidx; }
            }
        }
    }
#pragma unroll
    for (int m = 0; m < 4; ++m) { rv[ty * 4 + m][tx] = minv[m]; ri[ty * 4 + m][tx] = mini[m]; }
    __syncthreads();
    if (tid < 64) {
        float bv = rv[tid][0]; int bi = ri[tid][0];
#pragma unroll
        for (int j = 1; j < 16; ++j) {
            float v = rv[tid][j]; int ii = ri[tid][j];
            if (v < bv || (v == bv && ii < bi)) { bv = v; bi = ii; }
        }
        unsigned long long key =
            ((unsigned long long)__float_as_uint(bv) << 12) | (unsigned long long)bi;
        atomicMin(&keys[row0 + tid], key);
    }
}

// ================= downstream ==============================================

__global__ void count_kernel(const unsigned long long* __restrict__ keys,
                             float* __restrict__ counts)
{
    int i = blockIdx.x * 256 + threadIdx.x;
    int k = (int)(keys[i] & 0xFFFULL);
    atomicAdd(&counts[k], 1.0f);
}

__global__ __launch_bounds__(256) void ema_cluster_kernel(
    const float* __restrict__ hc, const float* __restrict__ counts,
    const float* __restrict__ countp, float* __restrict__ avgc, float* __restrict__ Nout)
{
    __shared__ float sm[256];
    int i = blockIdx.x * 256 + threadIdx.x;
    const float om = 1.0f - 0.99f;                  // matches reference's fp32 (one - decay)
    float bias = 1.0f - powf(0.99f, countp[0] + 1.0f);
    float a = (hc[i] * 0.99f + om * counts[i]) / bias;
    avgc[i] = a;
    sm[threadIdx.x] = a;
    __syncthreads();
    for (int s = 128; s > 0; s >>= 1) {
        if (threadIdx.x < s) sm[threadIdx.x] += sm[threadIdx.x + s];
        __syncthreads();
    }
    if (threadIdx.x == 0) atomicAdd(Nout, sm[0]);
}

// per-code gather of assigned x rows + EMA + codebook_new (no atomics, no dw buffer)
__global__ __launch_bounds__(256) void code_update_kernel(
    const float* __restrict__ x, const unsigned long long* __restrict__ keys,
    const float* __restrict__ hdw, const float* __restrict__ avgc,
    const float* __restrict__ Nptr, const float* __restrict__ countp,
    float* __restrict__ cbn)
{
    __shared__ unsigned short rows[2048];
    __shared__ int cnt;
    int k = blockIdx.x, tid = threadIdx.x;
    if (tid == 0) cnt = 0;
    __syncthreads();
    for (int j = 0; j < 64; ++j) {
        int i = j * 256 + tid;
        if ((int)(keys[i] & 0xFFFULL) == k) {
            int p = atomicAdd(&cnt, 1);
            if (p < 2048) rows[p] = (unsigned short)i;
        }
    }
    __syncthreads();
    int n = cnt < 2048 ? cnt : 2048;
    float a0 = 0.f, a1 = 0.f;
    for (int p = 0; p < n; ++p) {
        int r = rows[p];
        a0 += x[(size_t)r * D + tid];
        a1 += x[(size_t)r * D + tid + 256];
    }
    const float om = 1.0f - 0.99f;
    float bias = 1.0f - powf(0.99f, countp[0] + 1.0f);
    float Nv = *Nptr;
    float ccv = ((avgc[k] + 1e-5f) / (Nv + 0.04096f)) * Nv;
    size_t b = (size_t)k * D;
    cbn[b + tid]       = ((hdw[b + tid]       * 0.99f + om * a0) / bias) / ccv;
    cbn[b + tid + 256] = ((hdw[b + tid + 256] * 0.99f + om * a1) / bias) / ccv;
}

__global__ __launch_bounds__(256) void gather_kernel(
    const float* __restrict__ x, const unsigned long long* __restrict__ keys,
    const float* __restrict__ cbn, float* __restrict__ outq, double* __restrict__ sumsq)
{
    __shared__ float sm[256];
    int row = blockIdx.x;
    int tid = threadIdx.x;
    int k   = (int)(keys[row] & 0xFFFULL);
    const float* xp = x   + (size_t)row * D;
    const float* cp = cbn + (size_t)k   * D;
    float* op = outq + (size_t)row * D;
    float local = 0.f;
#pragma unroll
    for (int j = 0; j < 2; ++j) {
        int d = tid + j * 256;
        float xv = xp[d];
        float qv = cp[d];
        float quant = xv + (qv - xv);
        op[d] = quant;
        float diff = xv - quant;
        local = fmaf(diff, diff, local);
    }
    sm[tid] = local;
    __syncthreads();
    for (int s = 128; s > 0; s >>= 1) {
        if (tid < s) sm[tid] += sm[tid + s];
        __syncthreads();
    }
    if (tid == 0) atomicAdd(sumsq, (double)sm[0]);
}

__global__ void finalize_kernel(const unsigned long long* __restrict__ keys,
                                const double* __restrict__ sumsq, float* __restrict__ out)
{
    int i = blockIdx.x * 256 + threadIdx.x;
    out[8388609 + i] = (float)(keys[i] & 0xFFFULL);
    if (i == 0) out[8388608] = (float)(0.5 * (*sumsq) / 8388608.0);
}

// ================= launcher ================================================

extern "C" void kernel_launch(void* const* d_in, const int* in_sizes, int n_in,
                              void* d_out, int out_size, void* d_ws, size_t ws_size,
                              hipStream_t stream)
{
    const float* x   = (const float*)d_in[0];
    const float* cb  = (const float*)d_in[1];
    const float* hc  = (const float*)d_in[2];
    const float* hdw = (const float*)d_in[3];
    const float* cnt = (const float*)d_in[4];
    float* out = (float*)d_out;

    char* ws = (char*)d_ws;
    float*  c2     = (float*)(ws + OFF_C2);
    float*  x2     = (float*)(ws + OFF_X2);
    float*  counts = (float*)(ws + OFF_CNT);
    float*  avgc   = (float*)(ws + OFF_AVGC);
    double* sumsq  = (double*)(ws + OFF_SCAL);
    float*  Nout   = (float*)(ws + OFF_SCAL + 8);
    unsigned long long* keys = (unsigned long long*)(ws + OFF_KEYS);

    hipMemsetAsync(ws + OFF_CNT,  0,    (32 << 10) + 16, stream);  // counts/avgc/scalars
    hipMemsetAsync(ws + OFF_KEYS, 0xFF, BL * 8,          stream);  // keys = UINT64_MAX

    rowsq_kernel<<<K,  64, 0, stream>>>(cb, c2);
    rowsq_kernel<<<BL, 64, 0, stream>>>(x, x2);

    const bool primary = ws_size >= ((size_t)10 << 20);
    float* cbn;
    if (primary) {
        // x hi/lo splits live in d_out's quantized region (exactly 8388608 floats);
        // gather overwrites them at the end.
        unsigned short* gxh = (unsigned short*)d_out;
        unsigned short* gxl = gxh + (size_t)BL * D;
        unsigned short* gch = (unsigned short*)(ws + OFF_CH);
        unsigned short* gcl = (unsigned short*)(ws + OFF_CL);
        unsigned short* cand = (unsigned short*)(ws + OFF_CAND);
        cbn = (float*)(ws + OFF_CBN);

        split_kernel<<<(BL * D) / 2048, 256, 0, stream>>>(x,  gxh, gxl);
        split_kernel<<<(K  * D) / 2048, 256, 0, stream>>>(cb, gch, gcl);
        argmin_mfma<<<dim3(BL / 64, 4), 256, 0, stream>>>(gxh, gxl, gch, gcl, x2, c2, cand);
        rescore_kernel<<<(BL * 8) / 256, 256, 0, stream>>>(x, cb, x2, c2, cand, keys);
    } else {
        cbn = (float*)(ws + OFF_CBN_FB);
        argmin_fb<<<dim3(BL / 64, 4), 256, 0, stream>>>(x, cb, x2, c2, keys);
    }

    count_kernel<<<BL / 256, 256, 0, stream>>>(keys, counts);
    ema_cluster_kernel<<<K / 256, 256, 0, stream>>>(hc, counts, cnt, avgc, Nout);
    code_update_kernel<<<K, 256, 0, stream>>>(x, keys, hdw, avgc, Nout, cnt, cbn);
    gather_kernel<<<BL, 256, 0, stream>>>(x, keys, cbn, out, sumsq);
    finalize_kernel<<<BL / 256, 256, 0, stream>>>(keys, sumsq, out);
}

// Round 3
// 544.904 us; speedup vs baseline: 2.4437x; 1.3422x over previous
//
#include <hip/hip_runtime.h>
#include <math.h>

#define BL 16384
#define D  512
#define K  4096

// ---- ws layout (bytes) ----
#define OFF_C2    0                         // 4096 f
#define OFF_X2    (16<<10)                  // 16384 f (aliased as loss partials by gather)
#define OFF_CNT   (80<<10)                  // 4096 f
#define OFF_AVGC  (96<<10)                  // 4096 f
#define OFF_SCAL  (112<<10)                 // N float @+8 (legacy layout)
#define OFF_KEYS  (128<<10)                 // 16384 u64
#define OFF_CAND  (256<<10)                 // 16384*8 u16
#define OFF_CH    (512<<10)                 // K*D bf16
#define OFF_CL    ((512<<10) + K*D*2)       // K*D bf16
#define OFF_CBN   OFF_CH                    // K*D f32 (reuses ch/cl after argmin)
#define OFF_CBN_FB (256<<10)                // fallback cbn

typedef __bf16 bf16x8 __attribute__((ext_vector_type(8)));
typedef float  f32x4  __attribute__((ext_vector_type(4)));
#define MFMA(a,b,c) __builtin_amdgcn_mfma_f32_16x16x32_bf16(a,b,c,0,0,0)

// ================= bit-exact helpers (x2/c2 feed the exact rescore) =========

// fused: blocks 0..4095 -> codebook rows, 4096.. -> x rows. Inner arithmetic
// identical to round-1 rowsq (bit-exact requirement).
__global__ void rowsq_all(const float* __restrict__ x, const float* __restrict__ cb,
                          float* __restrict__ x2, float* __restrict__ c2)
{
    int b    = blockIdx.x;
    int lane = threadIdx.x;              // 64
    const float* p; float* o; int row;
    if (b < K) { p = cb; o = c2; row = b; }
    else       { p = x;  o = x2; row = b - K; }
    p += (size_t)row * D;
    float s = 0.f;
#pragma unroll
    for (int j = 0; j < D / 64; ++j) {
        float v = p[lane + j * 64];
        s = fmaf(v, v, s);
    }
#pragma unroll
    for (int off = 32; off > 0; off >>= 1)
        s += __shfl_down(s, off, 64);
    if (lane == 0) o[row] = s;
}

// ================= primary path ============================================

__device__ __forceinline__ unsigned short f2bf_rne(float f) {
    unsigned u = __float_as_uint(f);
    unsigned r = u + 0x7FFFu + ((u >> 16) & 1u);
    return (unsigned short)(r >> 16);
}

// fp32 -> (bf16 hi, bf16 lo), x and codebook in one dispatch
__global__ __launch_bounds__(256) void split_all(
    const float* __restrict__ x, const float* __restrict__ cb,
    unsigned short* __restrict__ xh, unsigned short* __restrict__ xl,
    unsigned short* __restrict__ ch, unsigned short* __restrict__ cl)
{
    int b = blockIdx.x;
    const float* src; unsigned short *h, *lo; size_t base;
    if (b < 4096) { src = x;  h = xh; lo = xl; base = ((size_t)b * 256 + threadIdx.x) * 8; }
    else          { src = cb; h = ch; lo = cl; base = ((size_t)(b - 4096) * 256 + threadIdx.x) * 8; }
    float4 v0 = *(const float4*)(src + base);
    float4 v1 = *(const float4*)(src + base + 4);
    float f[8] = {v0.x,v0.y,v0.z,v0.w,v1.x,v1.y,v1.z,v1.w};
    __align__(16) unsigned short hh[8], ll[8];
#pragma unroll
    for (int j = 0; j < 8; ++j) {
        unsigned short hb = f2bf_rne(f[j]);
        hh[j] = hb;
        float hf = __uint_as_float((unsigned)hb << 16);
        ll[j] = f2bf_rne(f[j] - hf);
    }
    *(uint4*)(h  + base) = *(const uint4*)hh;
    *(uint4*)(lo + base) = *(const uint4*)ll;
}

#define LDA 72   // ushort row stride: 64 data + 8 pad (16B-aligned rows, spreads banks)

// MFMA approx distance + per-split top-2 capture.
// v2: block tile 64 rows x 128 codes, 4 waves, wave tile 32x64 (2x4 of 16x16x32).
// 12 ds_read_b128 feed 24 MFMAs per wave-chunk (was 16:12) -> LDS bytes/MAC halved.
__global__ __launch_bounds__(256, 2) void argmin_mfma(
    const unsigned short* __restrict__ xh, const unsigned short* __restrict__ xl,
    const unsigned short* __restrict__ ch, const unsigned short* __restrict__ cl,
    const float* __restrict__ x2, const float* __restrict__ c2,
    unsigned short* __restrict__ cand)
{
    __shared__ __align__(16) unsigned short sAh[64 * LDA];
    __shared__ __align__(16) unsigned short sAl[64 * LDA];
    __shared__ __align__(16) unsigned short sBh[128 * LDA];
    __shared__ __align__(16) unsigned short sBl[128 * LDA];

    const int tid = threadIdx.x;
    const int l   = tid & 63;
    const int w   = tid >> 6;
    const int q   = l >> 4;          // quad
    const int c   = l & 15;          // col-lane
    const int wm  = w >> 1, wn = w & 1;
    const int row0 = blockIdx.x * 64;
    const int nb   = blockIdx.y * 1024;

    const int ar = tid >> 3;         // staging row 0..31
    const int kk = (tid & 7) * 8;    // staging k-offset

    // fragment LDS offsets (ushort units)
    int offA[2], offB[4];
#pragma unroll
    for (int tm = 0; tm < 2; ++tm) offA[tm] = (wm * 32 + tm * 16 + c) * LDA + q * 8;
#pragma unroll
    for (int tn = 0; tn < 4; ++tn) offB[tn] = (wn * 64 + tn * 16 + c) * LDA + q * 8;

    float x2r[8];
#pragma unroll
    for (int tm = 0; tm < 2; ++tm)
#pragma unroll
        for (int r = 0; r < 4; ++r)
            x2r[tm * 4 + r] = x2[row0 + wm * 32 + tm * 16 + q * 4 + r];

    float v1[8], v2[8]; unsigned i1[8], i2[8];
#pragma unroll
    for (int s = 0; s < 8; ++s) { v1[s] = v2[s] = 3.4028235e38f; i1[s] = i2[s] = 0; }

    for (int n0 = 0; n0 < 1024; n0 += 128) {
        f32x4 acc[2][4];
#pragma unroll
        for (int tm = 0; tm < 2; ++tm)
#pragma unroll
            for (int tn = 0; tn < 4; ++tn) { f32x4 z = {0.f,0.f,0.f,0.f}; acc[tm][tn] = z; }

        for (int d0 = 0; d0 < D; d0 += 64) {
            __syncthreads();   // prior readers done
            {
                size_t gx = (size_t)(row0 + ar) * D + d0 + kk;
                *(uint4*)&sAh[ar * LDA + kk]        = *(const uint4*)&xh[gx];
                *(uint4*)&sAh[(ar + 32) * LDA + kk] = *(const uint4*)&xh[gx + 32 * D];
                *(uint4*)&sAl[ar * LDA + kk]        = *(const uint4*)&xl[gx];
                *(uint4*)&sAl[(ar + 32) * LDA + kk] = *(const uint4*)&xl[gx + 32 * D];
                size_t gb = (size_t)(nb + n0 + ar) * D + d0 + kk;
#pragma unroll
                for (int j = 0; j < 4; ++j) {
                    *(uint4*)&sBh[(ar + 32 * j) * LDA + kk] = *(const uint4*)&ch[gb + (size_t)(32 * j) * D];
                    *(uint4*)&sBl[(ar + 32 * j) * LDA + kk] = *(const uint4*)&cl[gb + (size_t)(32 * j) * D];
                }
            }
            __syncthreads();
#pragma unroll
            for (int kh = 0; kh < 2; ++kh) {
                const int ko = kh * 32;
                bf16x8 ah[2], al[2], bh[4], bl[4];
#pragma unroll
                for (int tm = 0; tm < 2; ++tm) {
                    ah[tm] = *(const bf16x8*)&sAh[offA[tm] + ko];
                    al[tm] = *(const bf16x8*)&sAl[offA[tm] + ko];
                }
#pragma unroll
                for (int tn = 0; tn < 4; ++tn) {
                    bh[tn] = *(const bf16x8*)&sBh[offB[tn] + ko];
                    bl[tn] = *(const bf16x8*)&sBl[offB[tn] + ko];
                }
#pragma unroll
                for (int tm = 0; tm < 2; ++tm)
#pragma unroll
                    for (int tn = 0; tn < 4; ++tn) {
                        acc[tm][tn] = MFMA(ah[tm], bh[tn], acc[tm][tn]);
                        acc[tm][tn] = MFMA(ah[tm], bl[tn], acc[tm][tn]);
                        acc[tm][tn] = MFMA(al[tm], bh[tn], acc[tm][tn]);
                    }
            }
        }
        // epilogue: approx dd + running top-2 (C layout: col=lane&15, row=quad*4+reg)
#pragma unroll
        for (int tn = 0; tn < 4; ++tn) {
            unsigned col = nb + n0 + wn * 64 + tn * 16 + c;
            float c2v = c2[col];
#pragma unroll
            for (int tm = 0; tm < 2; ++tm)
#pragma unroll
                for (int r = 0; r < 4; ++r) {
                    int s = tm * 4 + r;
                    float dd = (x2r[s] - 2.0f * acc[tm][tn][r]) + c2v;
                    bool lt1 = (dd < v1[s]) || (dd == v1[s] && col < i1[s]);
                    bool lt2 = (dd < v2[s]) || (dd == v2[s] && col < i2[s]);
                    if (lt1)      { v2[s]=v1[s]; i2[s]=i1[s]; v1[s]=dd; i1[s]=col; }
                    else if (lt2) { v2[s]=dd;    i2[s]=col; }
                }
        }
    }

    // butterfly top-2 merge across the 16 col-lanes (same quad keeps same rows)
#pragma unroll
    for (int s = 0; s < 8; ++s) {
#pragma unroll
        for (int m = 1; m < 16; m <<= 1) {
            float    ov1 = __shfl_xor(v1[s], m, 64);
            unsigned oi1 = __shfl_xor(i1[s], m, 64);
            float    ov2 = __shfl_xor(v2[s], m, 64);
            unsigned oi2 = __shfl_xor(i2[s], m, 64);
            bool oLt = (ov1 < v1[s]) || (ov1 == v1[s] && oi1 < i1[s]);
            float    a1  = oLt ? ov1 : v1[s];  unsigned ai1 = oLt ? oi1 : i1[s];
            float    lf  = oLt ? v1[s] : ov1;  unsigned lfi = oLt ? i1[s] : oi1;
            float    ws_ = oLt ? ov2 : v2[s];  unsigned wsi = oLt ? oi2 : i2[s];
            bool s2 = (ws_ < lf) || (ws_ == lf && wsi < lfi);
            v2[s] = s2 ? ws_ : lf;  i2[s] = s2 ? wsi : lfi;
            v1[s] = a1;             i1[s] = ai1;
        }
    }

    // cross-wave merge (wn pairs share rows) via LDS, then write candidates
    __syncthreads();
    float*    mbv = (float*)sAh;            // [64][2][2]
    unsigned* mbi = (unsigned*)&sAh[2048];  // [64][2][2]
    if (c == 0) {
#pragma unroll
        for (int s = 0; s < 8; ++s) {
            int tm = s >> 2, r = s & 3;
            int rl = wm * 32 + tm * 16 + q * 4 + r;
            mbv[(rl * 2 + wn) * 2 + 0] = v1[s];  mbv[(rl * 2 + wn) * 2 + 1] = v2[s];
            mbi[(rl * 2 + wn) * 2 + 0] = i1[s];  mbi[(rl * 2 + wn) * 2 + 1] = i2[s];
        }
    }
    __syncthreads();
    if (tid < 64) {
        float    p1 = mbv[(tid*2+0)*2+0], p2 = mbv[(tid*2+0)*2+1];
        unsigned pi1 = mbi[(tid*2+0)*2+0], pi2 = mbi[(tid*2+0)*2+1];
        float    q1 = mbv[(tid*2+1)*2+0], q2 = mbv[(tid*2+1)*2+1];
        unsigned qi1 = mbi[(tid*2+1)*2+0], qi2 = mbi[(tid*2+1)*2+1];
        bool qLt = (q1 < p1) || (q1 == p1 && qi1 < pi1);
        float    b1  = qLt ? q1 : p1;   unsigned b1i = qLt ? qi1 : pi1;
        float    lf  = qLt ? p1 : q1;   unsigned lfi = qLt ? pi1 : qi1;
        float    ws_ = qLt ? q2 : p2;   unsigned wsi = qLt ? qi2 : pi2;
        bool s2 = (ws_ < lf) || (ws_ == lf && wsi < lfi);
        unsigned b2i = s2 ? wsi : lfi;
        size_t base = (size_t)(row0 + tid) * 8 + blockIdx.y * 2;
        cand[base + 0] = (unsigned short)b1i;
        cand[base + 1] = (unsigned short)b2i;
    }
}

// exact rescore, bit-identical arithmetic to round-1 (sequential fmaf k=0..511).
// 8 lanes/row; in-wave packed-u64 min == atomicMin of the same 8 keys. No atomics.
__global__ __launch_bounds__(256) void rescore_kernel(
    const float* __restrict__ x, const float* __restrict__ cb,
    const float* __restrict__ x2, const float* __restrict__ c2,
    const unsigned short* __restrict__ cand,
    unsigned long long* __restrict__ keys)
{
    int t = blockIdx.x * 256 + threadIdx.x;  // 131072
    int row = t >> 3, ci = t & 7;
    int idx = cand[(size_t)row * 8 + ci];
    const float* xp = x  + (size_t)row * D;
    const float* cp = cb + (size_t)idx * D;
    float acc = 0.f;
#pragma unroll 4
    for (int k0 = 0; k0 < D; k0 += 4) {
        float4 xv = *(const float4*)(xp + k0);
        float4 cv = *(const float4*)(cp + k0);
        acc = fmaf(xv.x, cv.x, acc);
        acc = fmaf(xv.y, cv.y, acc);
        acc = fmaf(xv.z, cv.z, acc);
        acc = fmaf(xv.w, cv.w, acc);
    }
    float wv = x2[row] - 2.0f * acc;
    float dd = wv + c2[idx];
    unsigned long long key =
        ((unsigned long long)__float_as_uint(dd) << 12) | (unsigned long long)idx;
#pragma unroll
    for (int m = 1; m < 8; m <<= 1) {
        unsigned long long o = __shfl_xor(key, m, 64);
        key = o < key ? o : key;
    }
    if ((t & 7) == 0) keys[row] = key;
}

// ================= fallback argmin (round-1 verbatim, proven) ===============
__global__ __launch_bounds__(256) void argmin_fb(
    const float* __restrict__ x, const float* __restrict__ cb,
    const float* __restrict__ x2, const float* __restrict__ c2,
    unsigned long long* __restrict__ keys)
{
    __shared__ __align__(16) float As[32][68];
    __shared__ __align__(16) float Bs[32][68];
    __shared__ float rv[64][16];
    __shared__ int   ri[64][16];

    const int tid  = threadIdx.x;
    const int tx   = tid & 15;
    const int ty   = tid >> 4;
    const int row0 = blockIdx.x * 64;
    const int nb   = blockIdx.y * 1024;

    float x2r[4];
#pragma unroll
    for (int m = 0; m < 4; ++m) x2r[m] = x2[row0 + ty * 4 + m];

    float minv[4]; int mini[4];
#pragma unroll
    for (int m = 0; m < 4; ++m) { minv[m] = 3.4028235e38f; mini[m] = 0; }

    for (int n0 = 0; n0 < 1024; n0 += 64) {
        float acc[4][4];
#pragma unroll
        for (int m = 0; m < 4; ++m)
#pragma unroll
            for (int n = 0; n < 4; ++n) acc[m][n] = 0.f;

        for (int d0 = 0; d0 < D; d0 += 32) {
            __syncthreads();
#pragma unroll
            for (int j = 0; j < 2; ++j) {
                int v   = j * 256 + tid;
                int row = v >> 3;
                int col = (v & 7) * 4;
                float4 av = *(const float4*)(x  + (size_t)(row0 + row) * D + d0 + col);
                As[col + 0][row] = av.x; As[col + 1][row] = av.y;
                As[col + 2][row] = av.z; As[col + 3][row] = av.w;
                float4 bv = *(const float4*)(cb + (size_t)(nb + n0 + row) * D + d0 + col);
                Bs[col + 0][row] = bv.x; Bs[col + 1][row] = bv.y;
                Bs[col + 2][row] = bv.z; Bs[col + 3][row] = bv.w;
            }
            __syncthreads();
#pragma unroll
            for (int kk = 0; kk < 32; ++kk) {
                float4 a4 = *(const float4*)&As[kk][ty * 4];
                float4 b4 = *(const float4*)&Bs[kk][tx * 4];
                float a_[4] = { a4.x, a4.y, a4.z, a4.w };
                float b_[4] = { b4.x, b4.y, b4.z, b4.w };
#pragma unroll
                for (int m = 0; m < 4; ++m)
#pragma unroll
                    for (int n = 0; n < 4; ++n)
                        acc[m][n] = fmaf(a_[m], b_[n], acc[m][n]);
            }
        }
#pragma unroll
        for (int n = 0; n < 4; ++n) {
            int kidx = nb + n0 + tx * 4 + n;
            float c2k = c2[kidx];
#pragma unroll
            for (int m = 0; m < 4; ++m) {
                float w  = x2r[m] - 2.0f * acc[m][n];
                float dd = w + c2k;
                if (dd < minv[m]) { minv[m] = dd; mini[m] = kidx; }
            }
        }
    }
#pragma unroll
    for (int m = 0; m < 4; ++m) { rv[ty * 4 + m][tx] = minv[m]; ri[ty * 4 + m][tx] = mini[m]; }
    __syncthreads();
    if (tid < 64) {
        float bv = rv[tid][0]; int bi = ri[tid][0];
#pragma unroll
        for (int j = 1; j < 16; ++j) {
            float v = rv[tid][j]; int ii = ri[tid][j];
            if (v < bv || (v == bv && ii < bi)) { bv = v; bi = ii; }
        }
        unsigned long long key =
            ((unsigned long long)__float_as_uint(bv) << 12) | (unsigned long long)bi;
        atomicMin(&keys[row0 + tid], key);
    }
}

// ================= downstream ==============================================

__global__ void count_kernel(const unsigned long long* __restrict__ keys,
                             float* __restrict__ counts)
{
    int i = blockIdx.x * 256 + threadIdx.x;
    int k = (int)(keys[i] & 0xFFFULL);
    atomicAdd(&counts[k], 1.0f);
}

__global__ __launch_bounds__(256) void ema_cluster_kernel(
    const float* __restrict__ hc, const float* __restrict__ counts,
    const float* __restrict__ countp, float* __restrict__ avgc, float* __restrict__ Nout)
{
    __shared__ float sm[256];
    int i = blockIdx.x * 256 + threadIdx.x;
    const float om = 1.0f - 0.99f;
    float bias = 1.0f - powf(0.99f, countp[0] + 1.0f);
    float a = (hc[i] * 0.99f + om * counts[i]) / bias;
    avgc[i] = a;
    sm[threadIdx.x] = a;
    __syncthreads();
    for (int s = 128; s > 0; s >>= 1) {
        if (threadIdx.x < s) sm[threadIdx.x] += sm[threadIdx.x + s];
        __syncthreads();
    }
    if (threadIdx.x == 0) atomicAdd(Nout, sm[0]);
}

// per-code gather of assigned x rows + EMA + codebook_new (no atomics)
__global__ __launch_bounds__(256) void code_update_kernel(
    const float* __restrict__ x, const unsigned long long* __restrict__ keys,
    const float* __restrict__ hdw, const float* __restrict__ avgc,
    const float* __restrict__ Nptr, const float* __restrict__ countp,
    float* __restrict__ cbn)
{
    __shared__ unsigned short rows[2048];
    __shared__ int cnt;
    int k = blockIdx.x, tid = threadIdx.x;
    if (tid == 0) cnt = 0;
    __syncthreads();
    for (int j = 0; j < 64; ++j) {
        int i = j * 256 + tid;
        if ((int)(keys[i] & 0xFFFULL) == k) {
            int p = atomicAdd(&cnt, 1);
            if (p < 2048) rows[p] = (unsigned short)i;
        }
    }
    __syncthreads();
    int n = cnt < 2048 ? cnt : 2048;
    float a0 = 0.f, a1 = 0.f;
    for (int p = 0; p < n; ++p) {
        int r = rows[p];
        a0 += x[(size_t)r * D + tid];
        a1 += x[(size_t)r * D + tid + 256];
    }
    const float om = 1.0f - 0.99f;
    float bias = 1.0f - powf(0.99f, countp[0] + 1.0f);
    float Nv = *Nptr;
    float ccv = ((avgc[k] + 1e-5f) / (Nv + 0.04096f)) * Nv;
    size_t b = (size_t)k * D;
    cbn[b + tid]       = ((hdw[b + tid]       * 0.99f + om * a0) / bias) / ccv;
    cbn[b + tid + 256] = ((hdw[b + tid + 256] * 0.99f + om * a1) / bias) / ccv;
}

// gather + per-block loss partial (NO global atomic) + index write
__global__ __launch_bounds__(256) void gather_kernel(
    const float* __restrict__ x, const unsigned long long* __restrict__ keys,
    const float* __restrict__ cbn, float* __restrict__ outq,
    float* __restrict__ partial)
{
    __shared__ float sm[256];
    int row = blockIdx.x;
    int tid = threadIdx.x;
    int k   = (int)(keys[row] & 0xFFFULL);
    const float* xp = x   + (size_t)row * D;
    const float* cp = cbn + (size_t)k   * D;
    float* op = outq + (size_t)row * D;
    float local = 0.f;
#pragma unroll
    for (int j = 0; j < 2; ++j) {
        int d = tid + j * 256;
        float xv = xp[d];
        float qv = cp[d];
        float quant = xv + (qv - xv);
        op[d] = quant;
        float diff = xv - quant;
        local = fmaf(diff, diff, local);
    }
    sm[tid] = local;
    __syncthreads();
    for (int s = 128; s > 0; s >>= 1) {
        if (tid < s) sm[tid] += sm[tid + s];
        __syncthreads();
    }
    if (tid == 0) {
        partial[row] = sm[0];
        outq[8388609 + row] = (float)k;   // index output
    }
}

// single-block fp64 reduction of 16384 partials -> loss scalar
__global__ __launch_bounds__(256) void finalize_kernel(
    const float* __restrict__ partial, float* __restrict__ out)
{
    __shared__ double sm[256];
    int tid = threadIdx.x;
    double s = 0.0;
#pragma unroll
    for (int j = 0; j < 64; ++j) s += (double)partial[tid + j * 256];
    sm[tid] = s;
    __syncthreads();
    for (int st = 128; st > 0; st >>= 1) {
        if (tid < st) sm[tid] += sm[tid + st];
        __syncthreads();
    }
    if (tid == 0) out[8388608] = (float)(0.5 * sm[0] / 8388608.0);
}

// ================= launcher ================================================

extern "C" void kernel_launch(void* const* d_in, const int* in_sizes, int n_in,
                              void* d_out, int out_size, void* d_ws, size_t ws_size,
                              hipStream_t stream)
{
    const float* x   = (const float*)d_in[0];
    const float* cb  = (const float*)d_in[1];
    const float* hc  = (const float*)d_in[2];
    const float* hdw = (const float*)d_in[3];
    const float* cnt = (const float*)d_in[4];
    float* out = (float*)d_out;

    char* ws = (char*)d_ws;
    float*  c2     = (float*)(ws + OFF_C2);
    float*  x2     = (float*)(ws + OFF_X2);
    float*  counts = (float*)(ws + OFF_CNT);
    float*  avgc   = (float*)(ws + OFF_AVGC);
    float*  Nout   = (float*)(ws + OFF_SCAL + 8);
    float*  partial= (float*)(ws + OFF_X2);   // aliases x2: x2 dead after rescore/argmin
    unsigned long long* keys = (unsigned long long*)(ws + OFF_KEYS);

    hipMemsetAsync(ws + OFF_CNT, 0, (32 << 10) + 16, stream);  // counts + scalars

    rowsq_all<<<K + BL, 64, 0, stream>>>(x, cb, x2, c2);

    const bool primary = ws_size >= ((size_t)10 << 20);
    float* cbn;
    if (primary) {
        // x hi/lo splits live in d_out's quantized region (8388608 floats),
        // overwritten by gather at the end.
        unsigned short* gxh = (unsigned short*)d_out;
        unsigned short* gxl = gxh + (size_t)BL * D;
        unsigned short* gch = (unsigned short*)(ws + OFF_CH);
        unsigned short* gcl = (unsigned short*)(ws + OFF_CL);
        unsigned short* cand = (unsigned short*)(ws + OFF_CAND);
        cbn = (float*)(ws + OFF_CBN);

        split_all<<<(BL * D + K * D) / 2048, 256, 0, stream>>>(x, cb, gxh, gxl, gch, gcl);
        argmin_mfma<<<dim3(BL / 64, 4), 256, 0, stream>>>(gxh, gxl, gch, gcl, x2, c2, cand);
        rescore_kernel<<<(BL * 8) / 256, 256, 0, stream>>>(x, cb, x2, c2, cand, keys);
    } else {
        cbn = (float*)(ws + OFF_CBN_FB);
        hipMemsetAsync(ws + OFF_KEYS, 0xFF, BL * 8, stream);
        argmin_fb<<<dim3(BL / 64, 4), 256, 0, stream>>>(x, cb, x2, c2, keys);
    }

    count_kernel<<<BL / 256, 256, 0, stream>>>(keys, counts);
    ema_cluster_kernel<<<K / 256, 256, 0, stream>>>(hc, counts, cnt, avgc, Nout);
    code_update_kernel<<<K, 256, 0, stream>>>(x, keys, hdw, avgc, Nout, cnt, cbn);
    gather_kernel<<<BL, 256, 0, stream>>>(x, keys, cbn, out, partial);
    finalize_kernel<<<1, 256, 0, stream>>>(partial, out);
}

// Round 5
// 374.396 us; speedup vs baseline: 3.5566x; 1.4554x over previous
//
#include <hip/hip_runtime.h>
#include <math.h>

#define BL 16384
#define D  512
#define K  4096
#define NCH 16          // chunks: 512 k / 32 k-per-chunk; per chunk-row: 8 granules x 16 B

// ---- ws layout (bytes) ----
#define OFF_C2    0                // 4096 f
#define OFF_X2    (16<<10)         // 16384 f (aliased as loss partials after rescore)
#define OFF_CNT   (80<<10)         // 4096 f
#define OFF_AVGC  (96<<10)         // 4096 f
#define OFF_SCAL  (112<<10)        // N float @+8
#define OFF_IDX16 (116<<10)        // 16384 u16
#define OFF_KEYS  (160<<10)        // 16384 u64
#define OFF_CAND  (288<<10)        // 16384*8 u16
#define OFF_CBP   (576<<10)        // cb' 16*4096*128 B = 8.39 MB; cbn (8 MB) reuses after argmin
#define OFF_CBN_FB (256<<10)       // fallback cbn

typedef __bf16 bf16x8 __attribute__((ext_vector_type(8)));
typedef float  f32x4  __attribute__((ext_vector_type(4)));
#define MFMA(a,b,c) __builtin_amdgcn_mfma_f32_16x16x32_bf16(a,b,c,0,0,0)

// ================= bit-exact helpers (feed exact rescore — DO NOT TOUCH) ====

__global__ void rowsq_all(const float* __restrict__ x, const float* __restrict__ cb,
                          float* __restrict__ x2, float* __restrict__ c2)
{
    int b    = blockIdx.x;
    int lane = threadIdx.x;              // 64
    const float* p; float* o; int row;
    if (b < K) { p = cb; o = c2; row = b; }
    else       { p = x;  o = x2; row = b - K; }
    p += (size_t)row * D;
    float s = 0.f;
#pragma unroll
    for (int j = 0; j < D / 64; ++j) {
        float v = p[lane + j * 64];
        s = fmaf(v, v, s);
    }
#pragma unroll
    for (int off = 32; off > 0; off >>= 1)
        s += __shfl_down(s, off, 64);
    if (lane == 0) o[row] = s;
}

// exact rescore, bit-identical arithmetic to round-1 (sequential fmaf k=0..511)
__global__ __launch_bounds__(256) void rescore_kernel(
    const float* __restrict__ x, const float* __restrict__ cb,
    const float* __restrict__ x2, const float* __restrict__ c2,
    const unsigned short* __restrict__ cand,
    unsigned long long* __restrict__ keys)
{
    int t = blockIdx.x * 256 + threadIdx.x;  // 131072
    int row = t >> 3, ci = t & 7;
    int idx = cand[(size_t)row * 8 + ci];
    const float* xp = x  + (size_t)row * D;
    const float* cp = cb + (size_t)idx * D;
    float acc = 0.f;
#pragma unroll 4
    for (int k0 = 0; k0 < D; k0 += 4) {
        float4 xv = *(const float4*)(xp + k0);
        float4 cv = *(const float4*)(cp + k0);
        acc = fmaf(xv.x, cv.x, acc);
        acc = fmaf(xv.y, cv.y, acc);
        acc = fmaf(xv.z, cv.z, acc);
        acc = fmaf(xv.w, cv.w, acc);
    }
    float wv = x2[row] - 2.0f * acc;
    float dd = wv + c2[idx];
    unsigned long long key =
        ((unsigned long long)__float_as_uint(dd) << 12) | (unsigned long long)idx;
#pragma unroll
    for (int m = 1; m < 8; m <<= 1) {
        unsigned long long o = __shfl_xor(key, m, 64);
        key = o < key ? o : key;
    }
    if ((t & 7) == 0) keys[row] = key;
}

// ================= primary path ============================================

__device__ __forceinline__ unsigned short f2bf_rne(float f) {
    unsigned u = __float_as_uint(f);
    unsigned r = u + 0x7FFFu + ((u >> 16) & 1u);
    return (unsigned short)(r >> 16);
}

__device__ __forceinline__ void load_lds16(const unsigned short* g, unsigned short* l) {
    __builtin_amdgcn_global_load_lds(
        (const __attribute__((address_space(1))) unsigned int*)(g),
        (__attribute__((address_space(3))) unsigned int*)(l), 16, 0, 0);
}

// fp32 -> hi/lo bf16 granule streams.
// Layout: [chunk c in 0..15][row][phys granule p in 0..7] * 16 B.
// Logical granule j = p ^ (row&7); j = 2u+e: k-group u (k = 32c+8u..+7), e: 0=hi 1=lo.
// One wave handles 8 rows x 8 positions of one chunk -> 16 B/lane, coalesced stores.
__global__ __launch_bounds__(256) void split_interleave(
    const float* __restrict__ x, const float* __restrict__ cb,
    unsigned short* __restrict__ xp, unsigned short* __restrict__ cbp)
{
    int gw   = blockIdx.x * 4 + (threadIdx.x >> 6);  // global wave id, 0..40959
    int lane = threadIdx.x & 63;
    int rl   = lane >> 3;                            // row within 8-row group
    int p    = lane & 7;                             // physical granule position
    const float* src; unsigned short* dst; int nr, c, r0;
    if (gw < 32768) { c = gw >> 11; r0 = (gw & 2047) * 8; src = x;  dst = xp;  nr = BL; }
    else { int lw = gw - 32768; c = lw >> 9; r0 = (lw & 511) * 8; src = cb; dst = cbp; nr = K; }
    int r = r0 + rl;
    int j = p ^ rl;                 // r&7 == rl (r0 multiple of 8)
    int u = j >> 1, e = j & 1;
    const float* sp = src + (size_t)r * D + c * 32 + u * 8;
    float4 f0 = *(const float4*)sp, f1 = *(const float4*)(sp + 4);
    float f[8] = {f0.x,f0.y,f0.z,f0.w,f1.x,f1.y,f1.z,f1.w};
    __align__(16) unsigned short o[8];
#pragma unroll
    for (int i = 0; i < 8; ++i) {
        unsigned short h = f2bf_rne(f[i]);
        if (e == 0) o[i] = h;
        else {
            float hf = __uint_as_float((unsigned)h << 16);
            o[i] = f2bf_rne(f[i] - hf);
        }
    }
    size_t off = (size_t)(c * nr + r) * 64 + (size_t)p * 8;   // ushort units
    *(uint4*)(dst + off) = *(const uint4*)o;
}

// MFMA approx distance + per-split top-2.
// Block 128 rows x 128 codes, 4 waves (2x2), wave tile 64x64 = 4x4 of 16x16x32 bf16.
// Per chunk (32 k): 16 ds_read_b128 feed 48 MFMAs (products hh, hl, lh per tile).
// DMA staging (global_load_lds 16B), XOR-swizzled granules (conflict-free b128).
__global__ __launch_bounds__(256, 2) void argmin_mfma(
    const unsigned short* __restrict__ xp, const unsigned short* __restrict__ cbp,
    const float* __restrict__ x2, const float* __restrict__ c2,
    unsigned short* __restrict__ cand)
{
    __shared__ __align__(16) unsigned short sA[128 * 64];   // 16 KiB [row][phys granule]
    __shared__ __align__(16) unsigned short sB[128 * 64];   // 16 KiB

    const int tid = threadIdx.x;
    const int l   = tid & 63;
    const int w   = tid >> 6;
    const int wm  = w >> 1, wn = w & 1;
    const int q   = l >> 4;          // quad -> k-group within chunk
    const int cc  = l & 15;          // row/col lane
    const int row0 = blockIdx.x * 128;
    const int nb   = blockIdx.y * 1024;

    // chunk-invariant LDS byte offsets: [tile t][e: 0=hi 1=lo]
    int rdA[4][2], rdB[4][2];
#pragma unroll
    for (int t = 0; t < 4; ++t)
#pragma unroll
        for (int e = 0; e < 2; ++e) {
            int ra = wm * 64 + t * 16 + cc;
            int rb = wn * 64 + t * 16 + cc;
            rdA[t][e] = ra * 128 + ((((q << 1) | e)) ^ (ra & 7)) * 16;
            rdB[t][e] = rb * 128 + ((((q << 1) | e)) ^ (rb & 7)) * 16;
        }

    unsigned long long k1[16], k2[16];
#pragma unroll
    for (int s = 0; s < 16; ++s) { k1[s] = ~0ULL; k2[s] = ~0ULL; }

    for (int n0 = 0; n0 < 8; ++n0) {
        f32x4 acc[4][4];
#pragma unroll
        for (int tm = 0; tm < 4; ++tm)
#pragma unroll
            for (int tn = 0; tn < 4; ++tn) { f32x4 z = {0.f,0.f,0.f,0.f}; acc[tm][tn] = z; }

        for (int c = 0; c < NCH; ++c) {
            __syncthreads();   // prior chunk's readers done
            {
                size_t abase = ((size_t)c * BL + row0) * 64;
                size_t bbase = ((size_t)c * K + nb + n0 * 128) * 64;
#pragma unroll
                for (int i = 0; i < 4; ++i) {
                    int gi = i * 4 + w;          // 8-row group 0..15
                    load_lds16(xp  + abase + gi * 512 + l * 8, &sA[gi * 512 + l * 8]);
                    load_lds16(cbp + bbase + gi * 512 + l * 8, &sB[gi * 512 + l * 8]);
                }
            }
            __syncthreads();   // DMA drained (vmcnt(0) before barrier)
            bf16x8 Ah[4], Al[4], Bh[4], Bl[4];
#pragma unroll
            for (int t = 0; t < 4; ++t) {
                Ah[t] = *(const bf16x8*)((const char*)sA + rdA[t][0]);
                Al[t] = *(const bf16x8*)((const char*)sA + rdA[t][1]);
                Bh[t] = *(const bf16x8*)((const char*)sB + rdB[t][0]);
                Bl[t] = *(const bf16x8*)((const char*)sB + rdB[t][1]);
            }
#pragma unroll
            for (int tm = 0; tm < 4; ++tm)
#pragma unroll
                for (int tn = 0; tn < 4; ++tn) {
                    acc[tm][tn] = MFMA(Ah[tm], Bh[tn], acc[tm][tn]);
                    acc[tm][tn] = MFMA(Ah[tm], Bl[tn], acc[tm][tn]);
                    acc[tm][tn] = MFMA(Al[tm], Bh[tn], acc[tm][tn]);
                }
        }
        // epilogue: dd + running top-2 (C layout: col=lane&15, row=quad*4+reg)
        float c2v[4];
#pragma unroll
        for (int tn = 0; tn < 4; ++tn)
            c2v[tn] = c2[nb + n0 * 128 + wn * 64 + tn * 16 + cc];
#pragma unroll
        for (int tm = 0; tm < 4; ++tm)
#pragma unroll
            for (int r = 0; r < 4; ++r) {
                int s = tm * 4 + r;
                float x2v = x2[row0 + wm * 64 + tm * 16 + q * 4 + r];
#pragma unroll
                for (int tn = 0; tn < 4; ++tn) {
                    unsigned col = nb + n0 * 128 + wn * 64 + tn * 16 + cc;
                    float dd = (x2v - 2.0f * acc[tm][tn][r]) + c2v[tn];
                    unsigned long long key =
                        ((unsigned long long)__float_as_uint(dd) << 12) | col;
                    if (key < k1[s]) { k2[s] = k1[s]; k1[s] = key; }
                    else if (key < k2[s]) { k2[s] = key; }
                }
            }
    }

    // butterfly top-2 merge across the 16 col-lanes (quads keep their rows)
#pragma unroll
    for (int s = 0; s < 16; ++s) {
#pragma unroll
        for (int m = 1; m < 16; m <<= 1) {
            unsigned long long o1 = __shfl_xor(k1[s], m, 64);
            unsigned long long o2 = __shfl_xor(k2[s], m, 64);
            unsigned long long lf = k1[s] > o1 ? k1[s] : o1;   // loser of firsts
            unsigned long long ws_ = k2[s] < o2 ? k2[s] : o2;  // winner of seconds
            k1[s] = k1[s] < o1 ? k1[s] : o1;
            k2[s] = lf < ws_ ? lf : ws_;
        }
    }

    // cross-wave (wn) merge via LDS, then candidate write
    __syncthreads();
    unsigned long long* sc = (unsigned long long*)sA;   // [128 rows][2 wn][2] = 4 KiB
    if (cc == 0) {
#pragma unroll
        for (int s = 0; s < 16; ++s) {
            int rl = wm * 64 + (s >> 2) * 16 + q * 4 + (s & 3);
            sc[(rl * 2 + wn) * 2 + 0] = k1[s];
            sc[(rl * 2 + wn) * 2 + 1] = k2[s];
        }
    }
    __syncthreads();
    if (tid < 128) {
        unsigned long long pa1 = sc[(tid * 2 + 0) * 2 + 0], pa2 = sc[(tid * 2 + 0) * 2 + 1];
        unsigned long long pb1 = sc[(tid * 2 + 1) * 2 + 0], pb2 = sc[(tid * 2 + 1) * 2 + 1];
        unsigned long long m1 = pa1 < pb1 ? pa1 : pb1;
        unsigned long long lf = pa1 > pb1 ? pa1 : pb1;
        unsigned long long ws_ = pa2 < pb2 ? pa2 : pb2;
        unsigned long long m2 = lf < ws_ ? lf : ws_;
        size_t base = (size_t)(row0 + tid) * 8 + blockIdx.y * 2;
        cand[base + 0] = (unsigned short)(m1 & 0xFFFULL);
        cand[base + 1] = (unsigned short)(m2 & 0xFFFULL);
    }
}

// ================= fallback argmin (round-1 verbatim, proven) ===============
__global__ __launch_bounds__(256) void argmin_fb(
    const float* __restrict__ x, const float* __restrict__ cb,
    const float* __restrict__ x2, const float* __restrict__ c2,
    unsigned long long* __restrict__ keys)
{
    __shared__ __align__(16) float As[32][68];
    __shared__ __align__(16) float Bs[32][68];
    __shared__ float rv[64][16];
    __shared__ int   ri[64][16];

    const int tid  = threadIdx.x;
    const int tx   = tid & 15;
    const int ty   = tid >> 4;
    const int row0 = blockIdx.x * 64;
    const int nb   = blockIdx.y * 1024;

    float x2r[4];
#pragma unroll
    for (int m = 0; m < 4; ++m) x2r[m] = x2[row0 + ty * 4 + m];

    float minv[4]; int mini[4];
#pragma unroll
    for (int m = 0; m < 4; ++m) { minv[m] = 3.4028235e38f; mini[m] = 0; }

    for (int n0 = 0; n0 < 1024; n0 += 64) {
        float acc[4][4];
#pragma unroll
        for (int m = 0; m < 4; ++m)
#pragma unroll
            for (int n = 0; n < 4; ++n) acc[m][n] = 0.f;

        for (int d0 = 0; d0 < D; d0 += 32) {
            __syncthreads();
#pragma unroll
            for (int j = 0; j < 2; ++j) {
                int v   = j * 256 + tid;
                int row = v >> 3;
                int col = (v & 7) * 4;
                float4 av = *(const float4*)(x  + (size_t)(row0 + row) * D + d0 + col);
                As[col + 0][row] = av.x; As[col + 1][row] = av.y;
                As[col + 2][row] = av.z; As[col + 3][row] = av.w;
                float4 bv = *(const float4*)(cb + (size_t)(nb + n0 + row) * D + d0 + col);
                Bs[col + 0][row] = bv.x; Bs[col + 1][row] = bv.y;
                Bs[col + 2][row] = bv.z; Bs[col + 3][row] = bv.w;
            }
            __syncthreads();
#pragma unroll
            for (int kk = 0; kk < 32; ++kk) {
                float4 a4 = *(const float4*)&As[kk][ty * 4];
                float4 b4 = *(const float4*)&Bs[kk][tx * 4];
                float a_[4] = { a4.x, a4.y, a4.z, a4.w };
                float b_[4] = { b4.x, b4.y, b4.z, b4.w };
#pragma unroll
                for (int m = 0; m < 4; ++m)
#pragma unroll
                    for (int n = 0; n < 4; ++n)
                        acc[m][n] = fmaf(a_[m], b_[n], acc[m][n]);
            }
        }
#pragma unroll
        for (int n = 0; n < 4; ++n) {
            int kidx = nb + n0 + tx * 4 + n;
            float c2k = c2[kidx];
#pragma unroll
            for (int m = 0; m < 4; ++m) {
                float wv = x2r[m] - 2.0f * acc[m][n];
                float dd = wv + c2k;
                if (dd < minv[m]) { minv[m] = dd; mini[m] = kidx; }
            }
        }
    }
#pragma unroll
    for (int m = 0; m < 4; ++m) { rv[ty * 4 + m][tx] = minv[m]; ri[ty * 4 + m][tx] = mini[m]; }
    __syncthreads();
    if (tid < 64) {
        float bv = rv[tid][0]; int bi = ri[tid][0];
#pragma unroll
        for (int j = 1; j < 16; ++j) {
            float v = rv[tid][j]; int ii = ri[tid][j];
            if (v < bv || (v == bv && ii < bi)) { bv = v; bi = ii; }
        }
        unsigned long long key =
            ((unsigned long long)__float_as_uint(bv) << 12) | (unsigned long long)bi;
        atomicMin(&keys[row0 + tid], key);
    }
}

// ================= downstream ==============================================

__global__ void count_kernel(const unsigned long long* __restrict__ keys,
                             float* __restrict__ counts, unsigned short* __restrict__ idx16)
{
    int i = blockIdx.x * 256 + threadIdx.x;
    int k = (int)(keys[i] & 0xFFFULL);
    idx16[i] = (unsigned short)k;
    atomicAdd(&counts[k], 1.0f);
}

__global__ __launch_bounds__(256) void ema_cluster_kernel(
    const float* __restrict__ hc, const float* __restrict__ counts,
    const float* __restrict__ countp, float* __restrict__ avgc, float* __restrict__ Nout)
{
    __shared__ float sm[256];
    int i = blockIdx.x * 256 + threadIdx.x;
    const float om = 1.0f - 0.99f;
    float bias = 1.0f - powf(0.99f, countp[0] + 1.0f);
    float a = (hc[i] * 0.99f + om * counts[i]) / bias;
    avgc[i] = a;
    sm[threadIdx.x] = a;
    __syncthreads();
    for (int s = 128; s > 0; s >>= 1) {
        if (threadIdx.x < s) sm[threadIdx.x] += sm[threadIdx.x + s];
        __syncthreads();
    }
    if (threadIdx.x == 0) atomicAdd(Nout, sm[0]);
}

// per-code gather of assigned x rows + EMA + codebook_new (scans compact u16 idx)
__global__ __launch_bounds__(256) void code_update_kernel(
    const float* __restrict__ x, const unsigned short* __restrict__ idx16,
    const float* __restrict__ hdw, const float* __restrict__ avgc,
    const float* __restrict__ Nptr, const float* __restrict__ countp,
    float* __restrict__ cbn)
{
    __shared__ unsigned short rows[2048];
    __shared__ int cnt;
    int k = blockIdx.x, tid = threadIdx.x;
    if (tid == 0) cnt = 0;
    __syncthreads();
    const uint4* ip = (const uint4*)idx16;   // 2048 x (8 u16)
    for (int j = 0; j < 8; ++j) {
        int u = j * 256 + tid;
        uint4 v = ip[u];
        unsigned ww[4] = {v.x, v.y, v.z, v.w};
#pragma unroll
        for (int e = 0; e < 4; ++e) {
            int k0 = (int)(ww[e] & 0xFFFFu), k1 = (int)(ww[e] >> 16);
            if (k0 == k) { int p = atomicAdd(&cnt, 1); if (p < 2048) rows[p] = (unsigned short)(u * 8 + e * 2); }
            if (k1 == k) { int p = atomicAdd(&cnt, 1); if (p < 2048) rows[p] = (unsigned short)(u * 8 + e * 2 + 1); }
        }
    }
    __syncthreads();
    int n = cnt < 2048 ? cnt : 2048;
    float a0 = 0.f, a1 = 0.f;
    for (int p = 0; p < n; ++p) {
        int r = rows[p];
        a0 += x[(size_t)r * D + tid];
        a1 += x[(size_t)r * D + tid + 256];
    }
    const float om = 1.0f - 0.99f;
    float bias = 1.0f - powf(0.99f, countp[0] + 1.0f);
    float Nv = *Nptr;
    float ccv = ((avgc[k] + 1e-5f) / (Nv + 0.04096f)) * Nv;
    size_t b = (size_t)k * D;
    cbn[b + tid]       = ((hdw[b + tid]       * 0.99f + om * a0) / bias) / ccv;
    cbn[b + tid + 256] = ((hdw[b + tid + 256] * 0.99f + om * a1) / bias) / ccv;
}

__global__ __launch_bounds__(256) void gather_kernel(
    const float* __restrict__ x, const unsigned long long* __restrict__ keys,
    const float* __restrict__ cbn, float* __restrict__ outq,
    float* __restrict__ partial)
{
    __shared__ float sm[256];
    int row = blockIdx.x;
    int tid = threadIdx.x;
    int k   = (int)(keys[row] & 0xFFFULL);
    const float* xpp = x   + (size_t)row * D;
    const float* cp  = cbn + (size_t)k   * D;
    float* op = outq + (size_t)row * D;
    float local = 0.f;
#pragma unroll
    for (int j = 0; j < 2; ++j) {
        int d = tid + j * 256;
        float xv = xpp[d];
        float qv = cp[d];
        float quant = xv + (qv - xv);
        op[d] = quant;
        float diff = xv - quant;
        local = fmaf(diff, diff, local);
    }
    sm[tid] = local;
    __syncthreads();
    for (int s = 128; s > 0; s >>= 1) {
        if (tid < s) sm[tid] += sm[tid + s];
        __syncthreads();
    }
    if (tid == 0) {
        partial[row] = sm[0];
        outq[8388609 + row] = (float)k;
    }
}

__global__ __launch_bounds__(256) void finalize_kernel(
    const float* __restrict__ partial, float* __restrict__ out)
{
    __shared__ double sm[256];
    int tid = threadIdx.x;
    double s = 0.0;
#pragma unroll
    for (int j = 0; j < 64; ++j) s += (double)partial[tid + j * 256];
    sm[tid] = s;
    __syncthreads();
    for (int st = 128; st > 0; st >>= 1) {
        if (tid < st) sm[tid] += sm[tid + st];
        __syncthreads();
    }
    if (tid == 0) out[8388608] = (float)(0.5 * sm[0] / 8388608.0);
}

// ================= launcher ================================================

extern "C" void kernel_launch(void* const* d_in, const int* in_sizes, int n_in,
                              void* d_out, int out_size, void* d_ws, size_t ws_size,
                              hipStream_t stream)
{
    const float* x   = (const float*)d_in[0];
    const float* cb  = (const float*)d_in[1];
    const float* hc  = (const float*)d_in[2];
    const float* hdw = (const float*)d_in[3];
    const float* cnt = (const float*)d_in[4];
    float* out = (float*)d_out;

    char* ws = (char*)d_ws;
    float*  c2     = (float*)(ws + OFF_C2);
    float*  x2     = (float*)(ws + OFF_X2);
    float*  counts = (float*)(ws + OFF_CNT);
    float*  avgc   = (float*)(ws + OFF_AVGC);
    float*  Nout   = (float*)(ws + OFF_SCAL + 8);
    unsigned short* idx16 = (unsigned short*)(ws + OFF_IDX16);
    unsigned long long* keys = (unsigned long long*)(ws + OFF_KEYS);
    float*  partial= (float*)(ws + OFF_X2);   // x2 dead after rescore

    hipMemsetAsync(ws + OFF_CNT, 0, (32 << 10) + 16, stream);

    rowsq_all<<<K + BL, 64, 0, stream>>>(x, cb, x2, c2);

    const bool primary = ws_size >= ((size_t)10 << 20);
    float* cbn;
    if (primary) {
        // x' stream = 16*16384*128 B = 33,554,432 B: exactly d_out's quantized
        // region (8388608 f); gather overwrites it at the end. cb' = 8.39 MB in ws.
        unsigned short* gxp = (unsigned short*)d_out;
        unsigned short* gcp = (unsigned short*)(ws + OFF_CBP);
        unsigned short* cand = (unsigned short*)(ws + OFF_CAND);
        cbn = (float*)(ws + OFF_CBP);   // reuses cb' after argmin

        split_interleave<<<10240, 256, 0, stream>>>(x, cb, gxp, gcp);
        argmin_mfma<<<dim3(BL / 128, 4), 256, 0, stream>>>(gxp, gcp, x2, c2, cand);
        rescore_kernel<<<(BL * 8) / 256, 256, 0, stream>>>(x, cb, x2, c2, cand, keys);
    } else {
        cbn = (float*)(ws + OFF_CBN_FB);
        hipMemsetAsync(ws + OFF_KEYS, 0xFF, BL * 8, stream);
        argmin_fb<<<dim3(BL / 64, 4), 256, 0, stream>>>(x, cb, x2, c2, keys);
    }

    count_kernel<<<BL / 256, 256, 0, stream>>>(keys, counts, idx16);
    ema_cluster_kernel<<<K / 256, 256, 0, stream>>>(hc, counts, cnt, avgc, Nout);
    code_update_kernel<<<K, 256, 0, stream>>>(x, idx16, hdw, avgc, Nout, cnt, cbn);
    gather_kernel<<<BL, 256, 0, stream>>>(x, keys, cbn, out, partial);
    finalize_kernel<<<1, 256, 0, stream>>>(partial, out);
}